// Round 3
// baseline (251.669 us; speedup 1.0000x reference)
//
#include <hip/hip_runtime.h>
#include <hip/hip_bf16.h>

#define N_NODES 262144
#define NUM_C   256
#define DIM     128
#define NUM_G   128
#define GMAX    4     // 256 sorted nodes span >4 graphs ~never; fallback handles it
#define WPAD    136   // padded LDS row stride in shorts (272 B, 16B-aligned)

typedef short  bf16x8 __attribute__((ext_vector_type(8)));
typedef float  f32x4  __attribute__((ext_vector_type(4)));

__device__ __forceinline__ short f2b(float f) {
    __hip_bfloat16 h = __float2bfloat16(f);
    return *reinterpret_cast<short*>(&h);
}

// ---------------------------------------------------------------------------
// Prep: zero out, convert W fp32->bf16 (row-major, unpadded), compute c_sq,
// build cum_end[g] from the sorted batch. Grid: 128 x 256. (verified r1/r2)
// ---------------------------------------------------------------------------
__global__ void centroid_prep(const float* __restrict__ W,
                              const int* __restrict__ batch,
                              float* __restrict__ out,
                              short* __restrict__ Wb,
                              float* __restrict__ csq,
                              int* __restrict__ cum_end)
{
    const int t   = threadIdx.x;
    const int b   = blockIdx.x;
    const int gid = b * 256 + t;

    float w = W[gid];
    out[gid] = 0.f;
    Wb[gid] = f2b(w);

    __shared__ float red[256];
    red[t] = w * w;
    __syncthreads();
    for (int off = 64; off > 0; off >>= 1) {
        if ((t & 127) < off) red[t] += red[t + off];
        __syncthreads();
    }
    if (t == 0)   csq[2 * b]     = red[0];
    if (t == 128) csq[2 * b + 1] = red[128];

    long i0 = (long)gid * 8;
    int g = batch[i0];
    if (gid == 0) {
        for (int gg = 0; gg < g; ++gg) cum_end[gg] = 0;
    }
    for (int k = 0; k < 8; ++k) {
        long i = i0 + k;
        int gn = (i + 1 < N_NODES) ? batch[i + 1] : NUM_G;
        if (gn != g) {
            for (int gg = g; gg < gn; ++gg) cum_end[gg] = (int)(i + 1);
        }
        g = gn;
    }
}

// ---------------------------------------------------------------------------
// Main: 1024 blocks x 512 threads. Block = 256 nodes; wave = 32 nodes
// (2 subtiles of 16). r0's proven LDS-B inner loop, but W staged in TWO
// 128-centroid halves (34.8 KB instead of 69.6) with a restage barrier
// between ct 0..7 and ct 8..15.  lacc shrunk to GMAX=4 (4 KB), csq read
// straight from global (L2-hot).  LDS total 38.9 KB -> 4 blocks/CU =
// 32 waves/CU, 2x the residency of the 87 us r0 kernel, same inner loop.
// (r1/r2 showed B-from-global thrashes L1 and regresses; LDS-B stays.)
// __launch_bounds__(512,4): 4 blocks/CU -> 64-VGPR budget (r2: 52 regs, ok).
// dist = sqrt(max(xsq + csq - 2*cross, 0)); pooled via wave butterfly ->
// block LDS accumulator -> global atomics; finish divides by counts.
// ---------------------------------------------------------------------------
__global__ __launch_bounds__(512, 4) void centroid_main(
    const float* __restrict__ x,
    const int* __restrict__ batch,
    const short* __restrict__ Wb,
    const float* __restrict__ csq,
    float* __restrict__ out)
{
    __shared__ short wlds[128 * WPAD];        // 34816 B (one 128-centroid half)
    __shared__ float lacc[GMAX * NUM_C];      //  4096 B

    const int t  = threadIdx.x;
    const int nb = blockIdx.x << 8;           // 256 nodes per block

#pragma unroll
    for (int i = t; i < GMAX * NUM_C; i += 512) lacc[i] = 0.f;

    const int  gmin    = batch[nb];
    const int  span    = batch[nb + 255] - gmin + 1;
    const bool use_lds = (span <= GMAX);

    const int lane = t & 63;
    const int m16  = lane & 15;
    const int quad = lane >> 4;
    const int n0   = nb + (t >> 6) * 32;      // wave's 32 nodes

    // ---- A fragments (32 VGPRs) + row sum-of-squares ----
    bf16x8 a[2][4];
    float  pre[2][4];
    int    g0[2];
    bool   uni[2];
    int    grow[2][4];
#pragma unroll
    for (int s = 0; s < 2; ++s) {
        const float* xp = x + (long)(n0 + s * 16 + m16) * DIM + quad * 8;
        float ss = 0.f;
#pragma unroll
        for (int ks = 0; ks < 4; ++ks) {
            f32x4 u0 = *(const f32x4*)(xp + ks * 32);
            f32x4 u1 = *(const f32x4*)(xp + ks * 32 + 4);
            bf16x8 av;
#pragma unroll
            for (int j = 0; j < 4; ++j) {
                ss += u0[j] * u0[j] + u1[j] * u1[j];
                av[j]     = f2b(u0[j]);
                av[j + 4] = f2b(u1[j]);
            }
            a[s][ks] = av;
        }
        ss += __shfl_xor(ss, 16);
        ss += __shfl_xor(ss, 32);
#pragma unroll
        for (int r = 0; r < 4; ++r) pre[s][r] = __shfl(ss, quad * 4 + r);

        g0[s]  = batch[n0 + s * 16];
        uni[s] = (g0[s] == batch[n0 + s * 16 + 15]);
        if (!uni[s]) {
#pragma unroll
            for (int r = 0; r < 4; ++r) grow[s][r] = batch[n0 + s * 16 + quad * 4 + r];
        }
    }

    // ---- two W-halves: stage 128 centroids, run ct tiles, restage ----
#pragma unroll 1
    for (int h = 0; h < 2; ++h) {
        __syncthreads();   // h=0: lacc init visible; h=1: all reads of half0 done
        // stage half h: 128 rows x 128 dims bf16, padded rows
#pragma unroll
        for (int i = 0; i < 4; ++i) {
            int k = h * 2048 + i * 512 + t;   // chunk of 8 shorts
            bf16x8 v = *(const bf16x8*)(Wb + k * 8);
            *(bf16x8*)(wlds + ((k >> 4) & 127) * WPAD + (k & 15) * 8) = v;
        }
        __syncthreads();   // W half visible

#pragma unroll 2
        for (int ct = 0; ct < 8; ++ct) {
            const int c = h * 128 + ct * 16 + m16;
            const short* wp = wlds + (ct * 16 + m16) * WPAD + quad * 8;
            bf16x8 b0 = *(const bf16x8*)(wp);
            bf16x8 b1 = *(const bf16x8*)(wp + 32);
            bf16x8 b2 = *(const bf16x8*)(wp + 64);
            bf16x8 b3 = *(const bf16x8*)(wp + 96);
            const float cs = csq[c];          // L2-hot, ~400cy slack to use

#pragma unroll
            for (int s = 0; s < 2; ++s) {
                f32x4 acc = {0.f, 0.f, 0.f, 0.f};
                acc = __builtin_amdgcn_mfma_f32_16x16x32_bf16(a[s][0], b0, acc, 0, 0, 0);
                acc = __builtin_amdgcn_mfma_f32_16x16x32_bf16(a[s][1], b1, acc, 0, 0, 0);
                acc = __builtin_amdgcn_mfma_f32_16x16x32_bf16(a[s][2], b2, acc, 0, 0, 0);
                acc = __builtin_amdgcn_mfma_f32_16x16x32_bf16(a[s][3], b3, acc, 0, 0, 0);

                if (use_lds && uni[s]) {
                    float v = 0.f;
#pragma unroll
                    for (int r = 0; r < 4; ++r) {
                        float d2 = __builtin_fmaf(acc[r], -2.f, pre[s][r] + cs);
                        v += __builtin_amdgcn_sqrtf(__builtin_fmaxf(d2, 0.f));
                    }
                    v += __shfl_xor(v, 16);
                    v += __shfl_xor(v, 32);
                    if (quad == 0)
                        atomicAdd(&lacc[(g0[s] - gmin) * NUM_C + c], v);
                } else {
#pragma unroll
                    for (int r = 0; r < 4; ++r) {
                        float d2 = __builtin_fmaf(acc[r], -2.f, pre[s][r] + cs);
                        float d  = __builtin_amdgcn_sqrtf(__builtin_fmaxf(d2, 0.f));
                        int   g  = uni[s] ? g0[s] : grow[s][r];
                        if (use_lds) atomicAdd(&lacc[(g - gmin) * NUM_C + c], d);
                        else         atomicAdd(&out[g * NUM_C + c], d);
                    }
                }
            }
        }
    }

    __syncthreads();
    if (use_lds) {
        for (int i = t; i < span * NUM_C; i += 512)
            atomicAdd(&out[(gmin + (i >> 8)) * NUM_C + (i & 255)], lacc[i]);
    }
}

// ---------------------------------------------------------------------------
// Finish: divide sums by per-graph counts. Grid: 128 x 256.
// ---------------------------------------------------------------------------
__global__ void centroid_finish(float* __restrict__ out,
                                const int* __restrict__ cum_end)
{
    const int g = blockIdx.x;
    const int c = threadIdx.x;
    int cnt = cum_end[g] - (g ? cum_end[g - 1] : 0);
    float denom = (float)(cnt > 0 ? cnt : 1);
    out[g * NUM_C + c] /= denom;
}

extern "C" void kernel_launch(void* const* d_in, const int* in_sizes, int n_in,
                              void* d_out, int out_size, void* d_ws, size_t ws_size,
                              hipStream_t stream) {
    const float* x     = (const float*)d_in[0];
    const int*   batch = (const int*)d_in[1];
    const float* W     = (const float*)d_in[2];
    float*       out   = (float*)d_out;

    // workspace: Wb (64 KB) | csq (1 KB) | cum_end (512 B)
    short* Wb      = (short*)d_ws;
    float* csq     = (float*)((char*)d_ws + 65536);
    int*   cum_end = (int*)((char*)d_ws + 65536 + 1024);

    centroid_prep<<<128, 256, 0, stream>>>(W, batch, out, Wb, csq, cum_end);
    centroid_main<<<N_NODES / 256, 512, 0, stream>>>(x, batch, Wb, csq, out);
    centroid_finish<<<NUM_G, 256, 0, stream>>>(out, cum_end);
}

// Round 4
// 238.735 us; speedup vs baseline: 1.0542x; 1.0542x over previous
//
#include <hip/hip_runtime.h>
#include <hip/hip_bf16.h>

#define N_NODES 262144
#define NUM_C   256
#define DIM     128
#define NUM_G   128
#define GMAX    8
#define WPAD    136   // padded LDS row stride in shorts (272 B, 16B-aligned)

typedef short  bf16x8 __attribute__((ext_vector_type(8)));
typedef float  f32x4  __attribute__((ext_vector_type(4)));

__device__ __forceinline__ short f2b(float f) {
    __hip_bfloat16 h = __float2bfloat16(f);
    return *reinterpret_cast<short*>(&h);
}

// ---------------------------------------------------------------------------
// Prep: zero out, convert W fp32->bf16 (row-major, unpadded), compute c_sq,
// build cum_end[g] from the sorted batch. Grid: 128 x 256. (verified r1/r2)
// ---------------------------------------------------------------------------
__global__ void centroid_prep(const float* __restrict__ W,
                              const int* __restrict__ batch,
                              float* __restrict__ out,
                              short* __restrict__ Wb,
                              float* __restrict__ csq,
                              int* __restrict__ cum_end)
{
    const int t   = threadIdx.x;
    const int b   = blockIdx.x;
    const int gid = b * 256 + t;

    float w = W[gid];
    out[gid] = 0.f;
    Wb[gid] = f2b(w);

    __shared__ float red[256];
    red[t] = w * w;
    __syncthreads();
    for (int off = 64; off > 0; off >>= 1) {
        if ((t & 127) < off) red[t] += red[t + off];
        __syncthreads();
    }
    if (t == 0)   csq[2 * b]     = red[0];
    if (t == 128) csq[2 * b + 1] = red[128];

    long i0 = (long)gid * 8;
    int g = batch[i0];
    if (gid == 0) {
        for (int gg = 0; gg < g; ++gg) cum_end[gg] = 0;
    }
    for (int k = 0; k < 8; ++k) {
        long i = i0 + k;
        int gn = (i + 1 < N_NODES) ? batch[i + 1] : NUM_G;
        if (gn != g) {
            for (int gg = g; gg < gn; ++gg) cum_end[gg] = (int)(i + 1);
        }
        g = gn;
    }
}

// ---------------------------------------------------------------------------
// Main: 512 blocks x 1024 threads. Block = 512 nodes; wave = 32 nodes
// (2 subtiles of 16).  EXACTLY the r0 structure (87 us @ 16 waves/CU):
// whole bf16 W staged once in padded LDS BEFORE A-fragments are built
// (disjoint live ranges -> no spill; r3's restage-inside-loop overlapped
// staging with a[] and spilled 21 MB), A-fragments persistent in VGPRs,
// 8 MFMAs per B-set.  Only change: block doubled to 1024 threads so
// 2 blocks/CU = 32 waves/CU (r0 had 2 blocks x 8 waves = 16) — LDS is
// 78.8 KB either way; the bigger block packs twice the waves under it.
// __launch_bounds__(1024, 2): 2 blocks/CU -> 8 waves/EU -> 64-VGPR budget
// (this body compiled to 52 under that budget in r0/r2).
// dist = sqrt(max(xsq + csq - 2*cross, 0)); pooled via wave butterfly ->
// block LDS accumulator -> global atomics; finish divides by counts.
// ---------------------------------------------------------------------------
__global__ __launch_bounds__(1024, 2) void centroid_main(
    const float* __restrict__ x,
    const int* __restrict__ batch,
    const short* __restrict__ Wb,
    const float* __restrict__ csq,
    float* __restrict__ out)
{
    __shared__ short wlds[NUM_C * WPAD];      // 69632 B
    __shared__ float lacc[GMAX * NUM_C];      //  8192 B
    __shared__ float csq_l[NUM_C];            //  1024 B

    const int t  = threadIdx.x;
    const int nb = blockIdx.x << 9;           // 512 nodes per block

    // ---- stage whole W (bf16) into padded LDS, coalesced global reads ----
#pragma unroll
    for (int i = 0; i < 4; ++i) {
        int k = i * 1024 + t;                 // chunk of 8 shorts, 4096 total
        bf16x8 v = *(const bf16x8*)(Wb + k * 8);
        *(bf16x8*)(wlds + (k >> 4) * WPAD + (k & 15) * 8) = v;
    }
    if (t < NUM_C) csq_l[t] = csq[t];
#pragma unroll
    for (int i = t; i < GMAX * NUM_C; i += 1024) lacc[i] = 0.f;

    const int  gmin    = batch[nb];
    const int  span    = batch[nb + 511] - gmin + 1;
    const bool use_lds = (span <= GMAX);

    const int lane = t & 63;
    const int m16  = lane & 15;
    const int quad = lane >> 4;
    const int n0   = nb + (t >> 6) * 32;      // wave's 32 nodes

    // ---- A fragments (32 VGPRs) + row sum-of-squares ----
    bf16x8 a[2][4];
    float  pre[2][4];
    int    g0[2];
    bool   uni[2];
    int    grow[2][4];
#pragma unroll
    for (int s = 0; s < 2; ++s) {
        const float* xp = x + (long)(n0 + s * 16 + m16) * DIM + quad * 8;
        float ss = 0.f;
#pragma unroll
        for (int ks = 0; ks < 4; ++ks) {
            f32x4 u0 = *(const f32x4*)(xp + ks * 32);
            f32x4 u1 = *(const f32x4*)(xp + ks * 32 + 4);
            bf16x8 av;
#pragma unroll
            for (int j = 0; j < 4; ++j) {
                ss += u0[j] * u0[j] + u1[j] * u1[j];
                av[j]     = f2b(u0[j]);
                av[j + 4] = f2b(u1[j]);
            }
            a[s][ks] = av;
        }
        ss += __shfl_xor(ss, 16);
        ss += __shfl_xor(ss, 32);
#pragma unroll
        for (int r = 0; r < 4; ++r) pre[s][r] = __shfl(ss, quad * 4 + r);

        g0[s]  = batch[n0 + s * 16];
        uni[s] = (g0[s] == batch[n0 + s * 16 + 15]);
        if (!uni[s]) {
#pragma unroll
            for (int r = 0; r < 4; ++r) grow[s][r] = batch[n0 + s * 16 + quad * 4 + r];
        }
    }

    __syncthreads();   // W staging + lacc init visible

    // ---- column-tile loop: B from LDS ----
#pragma unroll 2
    for (int ct = 0; ct < 16; ++ct) {
        const int c = ct * 16 + m16;
        const short* wp = wlds + c * WPAD + quad * 8;
        bf16x8 b0 = *(const bf16x8*)(wp);
        bf16x8 b1 = *(const bf16x8*)(wp + 32);
        bf16x8 b2 = *(const bf16x8*)(wp + 64);
        bf16x8 b3 = *(const bf16x8*)(wp + 96);
        const float cs = csq_l[c];

#pragma unroll
        for (int s = 0; s < 2; ++s) {
            f32x4 acc = {0.f, 0.f, 0.f, 0.f};
            acc = __builtin_amdgcn_mfma_f32_16x16x32_bf16(a[s][0], b0, acc, 0, 0, 0);
            acc = __builtin_amdgcn_mfma_f32_16x16x32_bf16(a[s][1], b1, acc, 0, 0, 0);
            acc = __builtin_amdgcn_mfma_f32_16x16x32_bf16(a[s][2], b2, acc, 0, 0, 0);
            acc = __builtin_amdgcn_mfma_f32_16x16x32_bf16(a[s][3], b3, acc, 0, 0, 0);

            if (use_lds && uni[s]) {
                float v = 0.f;
#pragma unroll
                for (int r = 0; r < 4; ++r) {
                    float d2 = __builtin_fmaf(acc[r], -2.f, pre[s][r] + cs);
                    v += __builtin_amdgcn_sqrtf(__builtin_fmaxf(d2, 0.f));
                }
                v += __shfl_xor(v, 16);
                v += __shfl_xor(v, 32);
                if (quad == 0)
                    atomicAdd(&lacc[(g0[s] - gmin) * NUM_C + c], v);
            } else {
#pragma unroll
                for (int r = 0; r < 4; ++r) {
                    float d2 = __builtin_fmaf(acc[r], -2.f, pre[s][r] + cs);
                    float d  = __builtin_amdgcn_sqrtf(__builtin_fmaxf(d2, 0.f));
                    int   g  = uni[s] ? g0[s] : grow[s][r];
                    if (use_lds) atomicAdd(&lacc[(g - gmin) * NUM_C + c], d);
                    else         atomicAdd(&out[g * NUM_C + c], d);
                }
            }
        }
    }

    __syncthreads();
    if (use_lds) {
        for (int i = t; i < span * NUM_C; i += 1024)
            atomicAdd(&out[(gmin + (i >> 8)) * NUM_C + (i & 255)], lacc[i]);
    }
}

// ---------------------------------------------------------------------------
// Finish: divide sums by per-graph counts. Grid: 128 x 256.
// ---------------------------------------------------------------------------
__global__ void centroid_finish(float* __restrict__ out,
                                const int* __restrict__ cum_end)
{
    const int g = blockIdx.x;
    const int c = threadIdx.x;
    int cnt = cum_end[g] - (g ? cum_end[g - 1] : 0);
    float denom = (float)(cnt > 0 ? cnt : 1);
    out[g * NUM_C + c] /= denom;
}

extern "C" void kernel_launch(void* const* d_in, const int* in_sizes, int n_in,
                              void* d_out, int out_size, void* d_ws, size_t ws_size,
                              hipStream_t stream) {
    const float* x     = (const float*)d_in[0];
    const int*   batch = (const int*)d_in[1];
    const float* W     = (const float*)d_in[2];
    float*       out   = (float*)d_out;

    // workspace: Wb (64 KB) | csq (1 KB) | cum_end (512 B)
    short* Wb      = (short*)d_ws;
    float* csq     = (float*)((char*)d_ws + 65536);
    int*   cum_end = (int*)((char*)d_ws + 65536 + 1024);

    centroid_prep<<<128, 256, 0, stream>>>(W, batch, out, Wb, csq, cum_end);
    centroid_main<<<N_NODES / 512, 1024, 0, stream>>>(x, batch, Wb, csq, out);
    centroid_finish<<<NUM_G, 256, 0, stream>>>(out, cum_end);
}

// Round 5
// 224.550 us; speedup vs baseline: 1.1208x; 1.0632x over previous
//
#include <hip/hip_runtime.h>
#include <hip/hip_bf16.h>

#define N_NODES 262144
#define NUM_C   256
#define DIM     128
#define NUM_G   128
#define GMAX    8
#define WPAD    136   // padded LDS row stride in shorts (272 B, 16B-aligned)

typedef short  bf16x8 __attribute__((ext_vector_type(8)));
typedef float  f32x4  __attribute__((ext_vector_type(4)));

__device__ __forceinline__ short f2b(float f) {
    __hip_bfloat16 h = __float2bfloat16(f);
    return *reinterpret_cast<short*>(&h);
}

// ---------------------------------------------------------------------------
// Prep: zero out, convert W fp32->bf16 (row-major, unpadded), compute c_sq,
// build cum_end[g] from the sorted batch. Grid: 128 x 256. (verified r1/r2)
// ---------------------------------------------------------------------------
__global__ void centroid_prep(const float* __restrict__ W,
                              const int* __restrict__ batch,
                              float* __restrict__ out,
                              short* __restrict__ Wb,
                              float* __restrict__ csq,
                              int* __restrict__ cum_end)
{
    const int t   = threadIdx.x;
    const int b   = blockIdx.x;
    const int gid = b * 256 + t;

    float w = W[gid];
    out[gid] = 0.f;
    Wb[gid] = f2b(w);

    __shared__ float red[256];
    red[t] = w * w;
    __syncthreads();
    for (int off = 64; off > 0; off >>= 1) {
        if ((t & 127) < off) red[t] += red[t + off];
        __syncthreads();
    }
    if (t == 0)   csq[2 * b]     = red[0];
    if (t == 128) csq[2 * b + 1] = red[128];

    long i0 = (long)gid * 8;
    int g = batch[i0];
    if (gid == 0) {
        for (int gg = 0; gg < g; ++gg) cum_end[gg] = 0;
    }
    for (int k = 0; k < 8; ++k) {
        long i = i0 + k;
        int gn = (i + 1 < N_NODES) ? batch[i + 1] : NUM_G;
        if (gn != g) {
            for (int gg = g; gg < gn; ++gg) cum_end[gg] = (int)(i + 1);
        }
        g = gn;
    }
}

// ---------------------------------------------------------------------------
// Main: 1024 blocks x 512 threads (r0 geometry — measured best at 87 us).
// SINGLE change vs r0: the __syncthreads() is moved BEFORE the A-fragment
// phase.  r0..r4 post-mortems showed the kernel is phase-serialized: with
// the barrier AFTER the x loads, s_waitcnt vmcnt(0)+s_barrier forces every
// wave to drain its ~900cy HBM loads and then wait for the block's slowest
// wave before ANY wave computes -> [mem-only burst][compute-only phase]
// alternation, all pipes <20% busy, and occupancy anti-correlated with
// perf (r1 82%/152us vs r0 29%/87us).  With the barrier moved, it only
// orders W staging (L2-hot, uniform); each wave's x loads issue after it
// and the wave enters the ct-loop when its OWN data lands -> waves
// de-stagger, memory and compute overlap across 8 waves x 2 blocks/CU.
// Correctness: staging/lacc-init/csq_l before barrier; LDS reads+atomics
// after; A-phase touches no LDS.
// dist = sqrt(max(xsq + csq - 2*cross, 0)); pooled via wave butterfly ->
// block LDS accumulator -> global atomics; finish divides by counts.
// ---------------------------------------------------------------------------
__global__ __launch_bounds__(512, 4) void centroid_main(
    const float* __restrict__ x,
    const int* __restrict__ batch,
    const short* __restrict__ Wb,
    const float* __restrict__ csq,
    float* __restrict__ out)
{
    __shared__ short wlds[NUM_C * WPAD];      // 69632 B
    __shared__ float lacc[GMAX * NUM_C];      //  8192 B
    __shared__ float csq_l[NUM_C];            //  1024 B

    const int t  = threadIdx.x;
    const int nb = blockIdx.x << 8;           // 256 nodes per block

    // ---- stage W (bf16) into padded LDS, coalesced global reads ----
#pragma unroll
    for (int i = 0; i < 8; ++i) {
        int k = i * 512 + t;                  // chunk of 8 shorts, 4096 total
        bf16x8 v = *(const bf16x8*)(Wb + k * 8);
        *(bf16x8*)(wlds + (k >> 4) * WPAD + (k & 15) * 8) = v;
    }
    if (t < NUM_C) csq_l[t] = csq[t];
#pragma unroll
    for (int i = t; i < GMAX * NUM_C; i += 512) lacc[i] = 0.f;

    const int  gmin    = batch[nb];
    const int  span    = batch[nb + 255] - gmin + 1;
    const bool use_lds = (span <= GMAX);

    const int lane = t & 63;
    const int m16  = lane & 15;
    const int quad = lane >> 4;
    const int n0   = nb + (t >> 6) * 32;      // wave's 32 nodes

    __syncthreads();   // W staging + lacc init visible; BEFORE the x loads

    // ---- A fragments (32 VGPRs) + row sum-of-squares (after barrier) ----
    bf16x8 a[2][4];
    float  pre[2][4];
    int    g0[2];
    bool   uni[2];
    int    grow[2][4];
#pragma unroll
    for (int s = 0; s < 2; ++s) {
        // graph ids first: issue early, cheap
        g0[s]  = batch[n0 + s * 16];
        uni[s] = (g0[s] == batch[n0 + s * 16 + 15]);
        if (!uni[s]) {
#pragma unroll
            for (int r = 0; r < 4; ++r) grow[s][r] = batch[n0 + s * 16 + quad * 4 + r];
        }

        const float* xp = x + (long)(n0 + s * 16 + m16) * DIM + quad * 8;
        float ss = 0.f;
#pragma unroll
        for (int ks = 0; ks < 4; ++ks) {
            f32x4 u0 = *(const f32x4*)(xp + ks * 32);
            f32x4 u1 = *(const f32x4*)(xp + ks * 32 + 4);
            bf16x8 av;
#pragma unroll
            for (int j = 0; j < 4; ++j) {
                ss += u0[j] * u0[j] + u1[j] * u1[j];
                av[j]     = f2b(u0[j]);
                av[j + 4] = f2b(u1[j]);
            }
            a[s][ks] = av;
        }
        ss += __shfl_xor(ss, 16);
        ss += __shfl_xor(ss, 32);
#pragma unroll
        for (int r = 0; r < 4; ++r) pre[s][r] = __shfl(ss, quad * 4 + r);
    }

    // ---- column-tile loop: B from LDS ----
#pragma unroll 2
    for (int ct = 0; ct < 16; ++ct) {
        const int c = ct * 16 + m16;
        const short* wp = wlds + c * WPAD + quad * 8;
        bf16x8 b0 = *(const bf16x8*)(wp);
        bf16x8 b1 = *(const bf16x8*)(wp + 32);
        bf16x8 b2 = *(const bf16x8*)(wp + 64);
        bf16x8 b3 = *(const bf16x8*)(wp + 96);
        const float cs = csq_l[c];

#pragma unroll
        for (int s = 0; s < 2; ++s) {
            f32x4 acc = {0.f, 0.f, 0.f, 0.f};
            acc = __builtin_amdgcn_mfma_f32_16x16x32_bf16(a[s][0], b0, acc, 0, 0, 0);
            acc = __builtin_amdgcn_mfma_f32_16x16x32_bf16(a[s][1], b1, acc, 0, 0, 0);
            acc = __builtin_amdgcn_mfma_f32_16x16x32_bf16(a[s][2], b2, acc, 0, 0, 0);
            acc = __builtin_amdgcn_mfma_f32_16x16x32_bf16(a[s][3], b3, acc, 0, 0, 0);

            if (use_lds && uni[s]) {
                float v = 0.f;
#pragma unroll
                for (int r = 0; r < 4; ++r) {
                    float d2 = __builtin_fmaf(acc[r], -2.f, pre[s][r] + cs);
                    v += __builtin_amdgcn_sqrtf(__builtin_fmaxf(d2, 0.f));
                }
                v += __shfl_xor(v, 16);
                v += __shfl_xor(v, 32);
                if (quad == 0)
                    atomicAdd(&lacc[(g0[s] - gmin) * NUM_C + c], v);
            } else {
#pragma unroll
                for (int r = 0; r < 4; ++r) {
                    float d2 = __builtin_fmaf(acc[r], -2.f, pre[s][r] + cs);
                    float d  = __builtin_amdgcn_sqrtf(__builtin_fmaxf(d2, 0.f));
                    int   g  = uni[s] ? g0[s] : grow[s][r];
                    if (use_lds) atomicAdd(&lacc[(g - gmin) * NUM_C + c], d);
                    else         atomicAdd(&out[g * NUM_C + c], d);
                }
            }
        }
    }

    __syncthreads();
    if (use_lds) {
        for (int i = t; i < span * NUM_C; i += 512)
            atomicAdd(&out[(gmin + (i >> 8)) * NUM_C + (i & 255)], lacc[i]);
    }
}

// ---------------------------------------------------------------------------
// Finish: divide sums by per-graph counts. Grid: 128 x 256.
// ---------------------------------------------------------------------------
__global__ void centroid_finish(float* __restrict__ out,
                                const int* __restrict__ cum_end)
{
    const int g = blockIdx.x;
    const int c = threadIdx.x;
    int cnt = cum_end[g] - (g ? cum_end[g - 1] : 0);
    float denom = (float)(cnt > 0 ? cnt : 1);
    out[g * NUM_C + c] /= denom;
}

extern "C" void kernel_launch(void* const* d_in, const int* in_sizes, int n_in,
                              void* d_out, int out_size, void* d_ws, size_t ws_size,
                              hipStream_t stream) {
    const float* x     = (const float*)d_in[0];
    const int*   batch = (const int*)d_in[1];
    const float* W     = (const float*)d_in[2];
    float*       out   = (float*)d_out;

    // workspace: Wb (64 KB) | csq (1 KB) | cum_end (512 B)
    short* Wb      = (short*)d_ws;
    float* csq     = (float*)((char*)d_ws + 65536);
    int*   cum_end = (int*)((char*)d_ws + 65536 + 1024);

    centroid_prep<<<128, 256, 0, stream>>>(W, batch, out, Wb, csq, cum_end);
    centroid_main<<<N_NODES / 256, 512, 0, stream>>>(x, batch, Wb, csq, out);
    centroid_finish<<<NUM_G, 256, 0, stream>>>(out, cum_end);
}

// Round 6
// 222.504 us; speedup vs baseline: 1.1311x; 1.0092x over previous
//
#include <hip/hip_runtime.h>
#include <hip/hip_bf16.h>

#define N_NODES 262144
#define NUM_C   256
#define DIM     128
#define NUM_G   128
#define GMAX    8
#define WPAD    136   // padded LDS row stride in shorts (272 B, 16B-aligned)

typedef short  bf16x8 __attribute__((ext_vector_type(8)));
typedef float  f32x4  __attribute__((ext_vector_type(4)));

__device__ __forceinline__ short f2b(float f) {
    __hip_bfloat16 h = __float2bfloat16(f);
    return *reinterpret_cast<short*>(&h);
}

// ---------------------------------------------------------------------------
// Prep: zero out, convert W fp32->bf16 (row-major, unpadded), compute c_sq,
// build cum_end[g] from the sorted batch. Grid: 128 x 256. (verified r1/r2)
// ---------------------------------------------------------------------------
__global__ void centroid_prep(const float* __restrict__ W,
                              const int* __restrict__ batch,
                              float* __restrict__ out,
                              short* __restrict__ Wb,
                              float* __restrict__ csq,
                              int* __restrict__ cum_end)
{
    const int t   = threadIdx.x;
    const int b   = blockIdx.x;
    const int gid = b * 256 + t;

    float w = W[gid];
    out[gid] = 0.f;
    Wb[gid] = f2b(w);

    __shared__ float red[256];
    red[t] = w * w;
    __syncthreads();
    for (int off = 64; off > 0; off >>= 1) {
        if ((t & 127) < off) red[t] += red[t + off];
        __syncthreads();
    }
    if (t == 0)   csq[2 * b]     = red[0];
    if (t == 128) csq[2 * b + 1] = red[128];

    long i0 = (long)gid * 8;
    int g = batch[i0];
    if (gid == 0) {
        for (int gg = 0; gg < g; ++gg) cum_end[gg] = 0;
    }
    for (int k = 0; k < 8; ++k) {
        long i = i0 + k;
        int gn = (i + 1 < N_NODES) ? batch[i + 1] : NUM_G;
        if (gn != g) {
            for (int gg = g; gg < gn; ++gg) cum_end[gg] = (int)(i + 1);
        }
        g = gn;
    }
}

// ---------------------------------------------------------------------------
// Main: 512 blocks x 512 threads, persistent over 4 chunks of 128 nodes
// (16 nodes/wave/chunk).  r0..r5 showed the kernel is memory-DUTY-CYCLE
// bound: all x loads issue in one burst, drain, then the ct-loop runs with
// zero memory traffic -> HBM averages 0.87 TB/s (66.6MB/77us ~= dur) while
// every pipe idles.  Fix: cross-chunk register pipelining — chunk k+1's
// 8 raw f32x4 loads (32 VGPR) stay IN FLIGHT during chunk k's ct-loop,
// converted to bf16 A-frags only after the loop.  HBM delivery becomes
// continuous (every wave keeps 8KB outstanding).
// Geometry: 2 blocks/CU (LDS 78.8KB x2 fits), __launch_bounds__(512,2)
// -> 128-VGPR budget (empirical: 2nd arg = blocks/CU; r1/r2/r3 evidence).
// Peak live set ~110 regs.  Epilogue identical to verified r0 math, s-dim
// dropped (one 16-node subtile per chunk).
// ---------------------------------------------------------------------------
__global__ __launch_bounds__(512, 2) void centroid_main(
    const float* __restrict__ x,
    const int* __restrict__ batch,
    const short* __restrict__ Wb,
    const float* __restrict__ csq,
    float* __restrict__ out)
{
    __shared__ short wlds[NUM_C * WPAD];      // 69632 B
    __shared__ float lacc[GMAX * NUM_C];      //  8192 B
    __shared__ float csq_l[NUM_C];            //  1024 B

    const int t  = threadIdx.x;
    const int nb = blockIdx.x << 9;           // 512 nodes per block

    // ---- stage W (bf16) into padded LDS, coalesced global reads ----
#pragma unroll
    for (int i = 0; i < 8; ++i) {
        int k = i * 512 + t;                  // chunk of 8 shorts, 4096 total
        bf16x8 v = *(const bf16x8*)(Wb + k * 8);
        *(bf16x8*)(wlds + (k >> 4) * WPAD + (k & 15) * 8) = v;
    }
    if (t < NUM_C) csq_l[t] = csq[t];
#pragma unroll
    for (int i = t; i < GMAX * NUM_C; i += 512) lacc[i] = 0.f;

    const int  gmin    = batch[nb];
    const int  span    = batch[nb + 511] - gmin + 1;
    const bool use_lds = (span <= GMAX);

    const int lane = t & 63;
    const int m16  = lane & 15;
    const int quad = lane >> 4;
    const int wid  = t >> 6;                  // wave id 0..7

    // per-chunk node base: nb + k*128 + wid*16; this lane's row = +m16
    const float* xbase = x + (long)(nb + wid * 16 + m16) * DIM + quad * 8;

    // ---- prologue: issue chunk0 raw loads (8 x f32x4 = 32 VGPR) ----
    f32x4 raw[8];
#pragma unroll
    for (int ks = 0; ks < 4; ++ks) {
        raw[2 * ks]     = *(const f32x4*)(xbase + ks * 32);
        raw[2 * ks + 1] = *(const f32x4*)(xbase + ks * 32 + 4);
    }

    __syncthreads();   // W staging + lacc init visible (drains chunk0 loads too)

    // ---- convert chunk0 -> A fragments + row sum-of-squares + meta ----
    bf16x8 a[4];
    float  pre[4];
    int    g0;
    bool   uni;
    int    grow[4];
    {
        float ss = 0.f;
#pragma unroll
        for (int ks = 0; ks < 4; ++ks) {
            f32x4 u0 = raw[2 * ks], u1 = raw[2 * ks + 1];
            bf16x8 av;
#pragma unroll
            for (int j = 0; j < 4; ++j) {
                ss += u0[j] * u0[j] + u1[j] * u1[j];
                av[j]     = f2b(u0[j]);
                av[j + 4] = f2b(u1[j]);
            }
            a[ks] = av;
        }
        ss += __shfl_xor(ss, 16);
        ss += __shfl_xor(ss, 32);
#pragma unroll
        for (int r = 0; r < 4; ++r) pre[r] = __shfl(ss, quad * 4 + r);

        const int cn = nb + wid * 16;
        g0  = batch[cn];
        uni = (g0 == batch[cn + 15]);
        if (!uni) {
#pragma unroll
            for (int r = 0; r < 4; ++r) grow[r] = batch[cn + quad * 4 + r];
        }
    }

    // ---- issue chunk1 raw loads (in flight through chunk0's ct-loop) ----
#pragma unroll
    for (int ks = 0; ks < 4; ++ks) {
        raw[2 * ks]     = *(const f32x4*)(xbase + 128 * DIM + ks * 32);
        raw[2 * ks + 1] = *(const f32x4*)(xbase + 128 * DIM + ks * 32 + 4);
    }

    // ---- chunk loop: compute chunk k while chunk k+1 streams in ----
#pragma unroll 1
    for (int k = 0; k < 4; ++k) {

#pragma unroll 2
        for (int ct = 0; ct < 16; ++ct) {
            const int c = ct * 16 + m16;
            const short* wp = wlds + c * WPAD + quad * 8;
            bf16x8 b0 = *(const bf16x8*)(wp);
            bf16x8 b1 = *(const bf16x8*)(wp + 32);
            bf16x8 b2 = *(const bf16x8*)(wp + 64);
            bf16x8 b3 = *(const bf16x8*)(wp + 96);
            const float cs = csq_l[c];

            f32x4 acc = {0.f, 0.f, 0.f, 0.f};
            acc = __builtin_amdgcn_mfma_f32_16x16x32_bf16(a[0], b0, acc, 0, 0, 0);
            acc = __builtin_amdgcn_mfma_f32_16x16x32_bf16(a[1], b1, acc, 0, 0, 0);
            acc = __builtin_amdgcn_mfma_f32_16x16x32_bf16(a[2], b2, acc, 0, 0, 0);
            acc = __builtin_amdgcn_mfma_f32_16x16x32_bf16(a[3], b3, acc, 0, 0, 0);

            if (use_lds && uni) {
                float v = 0.f;
#pragma unroll
                for (int r = 0; r < 4; ++r) {
                    float d2 = __builtin_fmaf(acc[r], -2.f, pre[r] + cs);
                    v += __builtin_amdgcn_sqrtf(__builtin_fmaxf(d2, 0.f));
                }
                v += __shfl_xor(v, 16);
                v += __shfl_xor(v, 32);
                if (quad == 0)
                    atomicAdd(&lacc[(g0 - gmin) * NUM_C + c], v);
            } else {
#pragma unroll
                for (int r = 0; r < 4; ++r) {
                    float d2 = __builtin_fmaf(acc[r], -2.f, pre[r] + cs);
                    float d  = __builtin_amdgcn_sqrtf(__builtin_fmaxf(d2, 0.f));
                    int   g  = uni ? g0 : grow[r];
                    if (use_lds) atomicAdd(&lacc[(g - gmin) * NUM_C + c], d);
                    else         atomicAdd(&out[g * NUM_C + c], d);
                }
            }
        }

        if (k < 3) {
            // convert chunk k+1 (raw arrived during the ct-loop above)
            float ss = 0.f;
#pragma unroll
            for (int ks = 0; ks < 4; ++ks) {
                f32x4 u0 = raw[2 * ks], u1 = raw[2 * ks + 1];
                bf16x8 av;
#pragma unroll
                for (int j = 0; j < 4; ++j) {
                    ss += u0[j] * u0[j] + u1[j] * u1[j];
                    av[j]     = f2b(u0[j]);
                    av[j + 4] = f2b(u1[j]);
                }
                a[ks] = av;
            }
            ss += __shfl_xor(ss, 16);
            ss += __shfl_xor(ss, 32);
#pragma unroll
            for (int r = 0; r < 4; ++r) pre[r] = __shfl(ss, quad * 4 + r);

            const int cn = nb + (k + 1) * 128 + wid * 16;
            g0  = batch[cn];
            uni = (g0 == batch[cn + 15]);
            if (!uni) {
#pragma unroll
                for (int r = 0; r < 4; ++r) grow[r] = batch[cn + quad * 4 + r];
            }

            // issue chunk k+2 loads (land during chunk k+1's ct-loop)
            if (k < 2) {
                const float* xp = xbase + (long)(k + 2) * 128 * DIM;
#pragma unroll
                for (int ks = 0; ks < 4; ++ks) {
                    raw[2 * ks]     = *(const f32x4*)(xp + ks * 32);
                    raw[2 * ks + 1] = *(const f32x4*)(xp + ks * 32 + 4);
                }
            }
        }
    }

    __syncthreads();
    if (use_lds) {
        for (int i = t; i < span * NUM_C; i += 512)
            atomicAdd(&out[(gmin + (i >> 8)) * NUM_C + (i & 255)], lacc[i]);
    }
}

// ---------------------------------------------------------------------------
// Finish: divide sums by per-graph counts. Grid: 128 x 256.
// ---------------------------------------------------------------------------
__global__ void centroid_finish(float* __restrict__ out,
                                const int* __restrict__ cum_end)
{
    const int g = blockIdx.x;
    const int c = threadIdx.x;
    int cnt = cum_end[g] - (g ? cum_end[g - 1] : 0);
    float denom = (float)(cnt > 0 ? cnt : 1);
    out[g * NUM_C + c] /= denom;
}

extern "C" void kernel_launch(void* const* d_in, const int* in_sizes, int n_in,
                              void* d_out, int out_size, void* d_ws, size_t ws_size,
                              hipStream_t stream) {
    const float* x     = (const float*)d_in[0];
    const int*   batch = (const int*)d_in[1];
    const float* W     = (const float*)d_in[2];
    float*       out   = (float*)d_out;

    // workspace: Wb (64 KB) | csq (1 KB) | cum_end (512 B)
    short* Wb      = (short*)d_ws;
    float* csq     = (float*)((char*)d_ws + 65536);
    int*   cum_end = (int*)((char*)d_ws + 65536 + 1024);

    centroid_prep<<<128, 256, 0, stream>>>(W, batch, out, Wb, csq, cum_end);
    centroid_main<<<N_NODES / 512, 512, 0, stream>>>(x, batch, Wb, csq, out);
    centroid_finish<<<NUM_G, 256, 0, stream>>>(out, cum_end);
}